// Round 4
// baseline (294.254 us; speedup 1.0000x reference)
//
#include <hip/hip_runtime.h>

// LoRA: out = x @ (A@B) * 1.0, computed as (x@A)@B.
// x: [M=16384, K=4096] f32, A: [K, 16] f32, B: [16, N=4096] f32.
constexpr int RANK = 16;
constexpr int K = 4096;
constexpr int N = 4096;
constexpr int M = 4 * 4096;
constexpr int KC = 512;       // K-chunk staged in LDS (512 rows x 64B = 32KB)
constexpr int NCHUNK = K / KC;
constexpr int ROWS2 = 32;     // rows per block in kernel 2

// ---------------- Kernel 1: T = x @ A ----------------
// Round-2 structure (known good) + register-prefetch double-buffered staging:
// chunk c+1's A float4s are global-loaded into regs DURING chunk c's compute,
// so the serial stage phase is only {barrier, ds_write_b128 x8, barrier}.
//
// LDS swizzle: slot s (floats 4s..4s+3) of row k stored at position
// p = s ^ ((k>>2)&3). Reader lane l (row k = kb+l, m=(l>>2)&3) reads
// position s^m to get true slot s (lane-uniform j), byte phases span all 8
// 16B-slots per 128B bank period -> conflict-free 8-phase wave64 ds_read_b128.
// Epilogue: recursive-halving reduce-scatter (63 shuffles) -> lane i holds
// element i of the wave's 4x16 tile -> one coalesced 256B store per wave.

__global__ __launch_bounds__(256) void lora_xa(const float* __restrict__ x,
                                               const float* __restrict__ A,
                                               float* __restrict__ T) {
  const int lane = threadIdx.x & 63;
  const int tid = threadIdx.x;
  const int wave = tid >> 6;
  const int r0 = blockIdx.x * 16 + wave * 4;  // this wave's 4 rows
  const int m = (lane >> 2) & 3;

  __shared__ float4 As[KC * 4];  // 32 KB, swizzled slots

  const float4* __restrict__ A4 = reinterpret_cast<const float4*>(A);

  float vals[64];
#pragma unroll
  for (int i = 0; i < 64; ++i) vals[i] = 0.0f;

  // Prefetch chunk 0 into registers.
  float4 cur[8];
#pragma unroll
  for (int q = 0; q < 8; ++q) cur[q] = A4[q * 256 + tid];

  for (int c = 0; c < NCHUNK; ++c) {
    __syncthreads();  // previous chunk's readers done
    // ---- write staged chunk to LDS (conflict-free b128 writes) ----
#pragma unroll
    for (int q = 0; q < 8; ++q) {
      const int n = q * 256 + tid;              // slot index 0..2047
      const int k = n >> 2;                     // local row
      const int s = n & 3;                      // true slot
      const int p = s ^ ((k >> 2) & 3);         // swizzled position
      As[k * 4 + p] = cur[q];
    }
    __syncthreads();

    // ---- issue next chunk's global loads (latency hides under compute) ----
    float4 nxt[8];
    if (c + 1 < NCHUNK) {
#pragma unroll
      for (int q = 0; q < 8; ++q)
        nxt[q] = A4[(size_t)(c + 1) * 2048 + q * 256 + tid];
    }

    // ---- compute: 8 k-blocks of 64 (one k per lane) ----
#pragma unroll
    for (int kbi = 0; kbi < 8; ++kbi) {
      const int kl = kbi * 64 + lane;           // local k in chunk
      const size_t kg = (size_t)c * KC + kl;    // global k

      float xv[4];
#pragma unroll
      for (int r = 0; r < 4; ++r) xv[r] = x[(size_t)(r0 + r) * K + kg];

      float4 a[4];
#pragma unroll
      for (int s = 0; s < 4; ++s) a[s] = As[kl * 4 + (s ^ m)];

#pragma unroll
      for (int r = 0; r < 4; ++r) {
#pragma unroll
        for (int s = 0; s < 4; ++s) {
          vals[r * 16 + 4 * s + 0] = fmaf(xv[r], a[s].x, vals[r * 16 + 4 * s + 0]);
          vals[r * 16 + 4 * s + 1] = fmaf(xv[r], a[s].y, vals[r * 16 + 4 * s + 1]);
          vals[r * 16 + 4 * s + 2] = fmaf(xv[r], a[s].z, vals[r * 16 + 4 * s + 2]);
          vals[r * 16 + 4 * s + 3] = fmaf(xv[r], a[s].w, vals[r * 16 + 4 * s + 3]);
        }
      }
    }

    // rotate prefetch buffer (register renames, no real moves)
#pragma unroll
    for (int q = 0; q < 8; ++q) cur[q] = nxt[q];
  }

  // Recursive-halving reduce-scatter across the 64 lanes.
  // After all steps, lane i holds the fully-summed element i (r=i>>4, j=i&15).
#define RSTEP(HALF)                                            \
  {                                                            \
    const bool hi = (lane & (HALF)) != 0;                      \
    _Pragma("unroll")                                          \
    for (int i = 0; i < (HALF); ++i) {                         \
      const float send = hi ? vals[i] : vals[i + (HALF)];      \
      const float keep = hi ? vals[i + (HALF)] : vals[i];      \
      vals[i] = keep + __shfl_xor(send, (HALF), 64);           \
    }                                                          \
  }
  RSTEP(32)
  RSTEP(16)
  RSTEP(8)
  RSTEP(4)
  RSTEP(2)
  RSTEP(1)
#undef RSTEP

  T[(size_t)(r0 + (lane >> 4)) * RANK + (lane & 15)] = vals[0];
}

// ---------------- Kernel 2: out = T @ B ----------------
// Each thread holds B[0..15][n0..n0+3] in 64 VGPRs (loaded once), then loops
// ROWS2 rows. T reads are block-uniform (scalar path); stores are coalesced
// float4 at 16B/lane. Near the ~6.9 TB/s write ceiling already.
__global__ __launch_bounds__(256) void lora_tb(const float* __restrict__ T,
                                               const float* __restrict__ B,
                                               float* __restrict__ out) {
  const int n0 = blockIdx.x * 1024 + threadIdx.x * 4;
  const int r0 = blockIdx.y * ROWS2;

  const float4* __restrict__ B4 = reinterpret_cast<const float4*>(B);
  float4* __restrict__ out4 = reinterpret_cast<float4*>(out);

  float4 b[16];
#pragma unroll
  for (int j = 0; j < RANK; ++j) b[j] = B4[((size_t)j * N + n0) >> 2];

  for (int r = 0; r < ROWS2; ++r) {
    const float* __restrict__ t = T + (size_t)(r0 + r) * RANK;
    float4 acc;
    acc.x = acc.y = acc.z = acc.w = 0.0f;
#pragma unroll
    for (int j = 0; j < RANK; ++j) {
      const float ts = t[j];
      acc.x = fmaf(ts, b[j].x, acc.x);
      acc.y = fmaf(ts, b[j].y, acc.y);
      acc.z = fmaf(ts, b[j].z, acc.z);
      acc.w = fmaf(ts, b[j].w, acc.w);
    }
    out4[((size_t)(r0 + r) * N + n0) >> 2] = acc;
  }
}

extern "C" void kernel_launch(void* const* d_in, const int* in_sizes, int n_in,
                              void* d_out, int out_size, void* d_ws, size_t ws_size,
                              hipStream_t stream) {
  const float* x = (const float*)d_in[0];   // [M, K]
  const float* A = (const float*)d_in[1];   // [K, RANK]
  const float* B = (const float*)d_in[2];   // [RANK, N]
  float* out = (float*)d_out;               // [M, N]
  float* T = (float*)d_ws;                  // [M, RANK] scratch (1 MiB)

  // Kernel 1: 16 rows per block (4 waves x 4 rows) -> 1024 blocks.
  lora_xa<<<M / 16, 256, 0, stream>>>(x, A, T);

  // Kernel 2: grid (N/1024, M/ROWS2).
  lora_tb<<<dim3(N / 1024, M / ROWS2), 256, 0, stream>>>(T, B, out);
}

// Round 5
// 162.521 us; speedup vs baseline: 1.8106x; 1.8106x over previous
//
#include <hip/hip_runtime.h>

// LoRA: out = x @ (A@B) * 1.0, computed as (x@A)@B.
// x: [M=16384, K=4096] f32, A: [K, 16] f32, B: [16, R=4096] f32.
constexpr int RANK = 16;
constexpr int K = 4096;
constexpr int N = 4096;
constexpr int M = 4 * 4096;
constexpr int KQ = 1024;         // K-quarter per xa block (A-quarter = 64KB LDS)
constexpr int NPART = K / KQ;    // 4 partials
constexpr int ROWSB = 32;        // M-rows per xa block (8 waves x 4 rows)
constexpr int ROWS2 = 32;        // rows per block in kernel 2

// ---------------- Kernel 1: Tp[part] = x[:, part] @ A[part, :] ----------------
// Block = 512 threads (8 waves), 32 rows, one K-quarter. Stage the 64KB
// A-quarter TRANSPOSED into LDS once (single barrier), then stream x with
// float4 loads and ZERO further barriers.
//
// LDS: AsT[j][k], j=0..15, k=0..1023 (64KB). Staging scatter-writes are b32
// with k-XOR swizzle kpos = k ^ ((j&7)<<2) -> 2 lanes/bank (free).
// Reads invert it as a float4-slot permutation slot = q4 ^ (j&7): lanes read
// a permutation of 64 consecutive 16B slots -> ideal 8-phase ds_read_b128,
// conflict-free.
// Epilogue: recursive-halving reduce-scatter (63 shuffles) -> lane i holds
// element i of the wave's 4x16 tile -> one coalesced 256B store per wave.

__global__ __launch_bounds__(512, 4) void lora_xa(const float* __restrict__ x,
                                                  const float* __restrict__ A,
                                                  float* __restrict__ Tp) {
  const int tid = threadIdx.x;
  const int lane = tid & 63;
  const int wave = tid >> 6;
  const int r0 = blockIdx.x * ROWSB + wave * 4;  // this wave's 4 rows
  const int part = blockIdx.y;                   // K-quarter index

  __shared__ float AsT[RANK][KQ];  // 64 KB, transposed + k-swizzled A quarter
  float4* __restrict__ AsT4 = reinterpret_cast<float4*>(&AsT[0][0]);

  const float4* __restrict__ A4 = reinterpret_cast<const float4*>(A);
  const float4* __restrict__ x4 = reinterpret_cast<const float4*>(x);

  // ---- one-time stage: 4096 float4 of A-quarter, 8 per thread ----
#pragma unroll
  for (int q = 0; q < 8; ++q) {
    const int n = q * 512 + tid;            // n = k*4 + s, 0..4095
    const int k = n >> 2;                   // local k row 0..1023
    const int s = n & 3;                    // j-group (cols 4s..4s+3)
    const float4 v = A4[(size_t)part * 4096 + n];  // coalesced
    AsT[4 * s + 0][k ^ (((4 * s + 0) & 7) << 2)] = v.x;
    AsT[4 * s + 1][k ^ (((4 * s + 1) & 7) << 2)] = v.y;
    AsT[4 * s + 2][k ^ (((4 * s + 2) & 7) << 2)] = v.z;
    AsT[4 * s + 3][k ^ (((4 * s + 3) & 7) << 2)] = v.w;
  }
  __syncthreads();  // the only barrier in the kernel

  float vals[64];
#pragma unroll
  for (int i = 0; i < 64; ++i) vals[i] = 0.0f;

  // ---- barrier-free stream: 4 steps x (4 rows x float4 + 16 j x b128) ----
#pragma unroll
  for (int step = 0; step < KQ / 256; ++step) {
    const int q4 = step * 64 + lane;  // this lane's true k-quad (k = 4*q4..)

    float4 xv[4];
#pragma unroll
    for (int r = 0; r < 4; ++r)
      xv[r] = x4[(size_t)(r0 + r) * (K / 4) + part * (KQ / 4) + q4];

#pragma unroll
    for (int jg = 0; jg < 4; ++jg) {
      float4 a[4];
#pragma unroll
      for (int jj = 0; jj < 4; ++jj) {
        const int j = 4 * jg + jj;
        a[jj] = AsT4[j * (KQ / 4) + (q4 ^ (j & 7))];  // swizzle-inverted
      }
#pragma unroll
      for (int r = 0; r < 4; ++r) {
#pragma unroll
        for (int jj = 0; jj < 4; ++jj) {
          float acc = vals[r * 16 + 4 * jg + jj];
          acc = fmaf(xv[r].x, a[jj].x, acc);
          acc = fmaf(xv[r].y, a[jj].y, acc);
          acc = fmaf(xv[r].z, a[jj].z, acc);
          acc = fmaf(xv[r].w, a[jj].w, acc);
          vals[r * 16 + 4 * jg + jj] = acc;
        }
      }
    }
  }

  // Recursive-halving reduce-scatter across the 64 lanes.
  // After all steps, lane i holds the fully-summed element i (r=i>>4, j=i&15).
#define RSTEP(HALF)                                            \
  {                                                            \
    const bool hi = (lane & (HALF)) != 0;                      \
    _Pragma("unroll")                                          \
    for (int i = 0; i < (HALF); ++i) {                         \
      const float send = hi ? vals[i] : vals[i + (HALF)];      \
      const float keep = hi ? vals[i + (HALF)] : vals[i];      \
      vals[i] = keep + __shfl_xor(send, (HALF), 64);           \
    }                                                          \
  }
  RSTEP(32)
  RSTEP(16)
  RSTEP(8)
  RSTEP(4)
  RSTEP(2)
  RSTEP(1)
#undef RSTEP

  // Tp[part][row][j], coalesced 256B per wave.
  Tp[(size_t)part * (M * RANK) + (size_t)(r0 + (lane >> 4)) * RANK + (lane & 15)] =
      vals[0];
}

// ---------------- Kernel 2: out = (sum_p Tp[p]) @ B ----------------
// Each thread holds B[0..15][n0..n0+3] in 64 VGPRs (loaded once), then loops
// ROWS2 rows. T-partial reads are block-uniform (scalar path); stores are
// coalesced float4 at 16B/lane. Near the ~6.9 TB/s write ceiling.
__global__ __launch_bounds__(256) void lora_tb(const float* __restrict__ Tp,
                                               const float* __restrict__ B,
                                               float* __restrict__ out) {
  const int n0 = blockIdx.x * 1024 + threadIdx.x * 4;
  const int r0 = blockIdx.y * ROWS2;

  const float4* __restrict__ B4 = reinterpret_cast<const float4*>(B);
  const float4* __restrict__ Tq = reinterpret_cast<const float4*>(Tp);
  float4* __restrict__ out4 = reinterpret_cast<float4*>(out);

  float4 b[16];
#pragma unroll
  for (int j = 0; j < RANK; ++j) b[j] = B4[((size_t)j * N + n0) >> 2];

  for (int r = 0; r < ROWS2; ++r) {
    // t row = sum of 4 partials (uniform loads, f32 accumulate)
    float4 t[4];
#pragma unroll
    for (int jg = 0; jg < 4; ++jg) {
      float4 acc = Tq[((size_t)0 * M + (r0 + r)) * 4 + jg];
#pragma unroll
      for (int p = 1; p < NPART; ++p) {
        const float4 v = Tq[((size_t)p * M + (r0 + r)) * 4 + jg];
        acc.x += v.x; acc.y += v.y; acc.z += v.z; acc.w += v.w;
      }
      t[jg] = acc;
    }

    float4 acc;
    acc.x = acc.y = acc.z = acc.w = 0.0f;
#pragma unroll
    for (int jg = 0; jg < 4; ++jg) {
#pragma unroll
      for (int jj = 0; jj < 4; ++jj) {
        const int j = 4 * jg + jj;
        const float ts = (jj == 0) ? t[jg].x : (jj == 1) ? t[jg].y
                        : (jj == 2) ? t[jg].z : t[jg].w;
        acc.x = fmaf(ts, b[j].x, acc.x);
        acc.y = fmaf(ts, b[j].y, acc.y);
        acc.z = fmaf(ts, b[j].z, acc.z);
        acc.w = fmaf(ts, b[j].w, acc.w);
      }
    }
    out4[((size_t)(r0 + r) * N + n0) >> 2] = acc;
  }
}

extern "C" void kernel_launch(void* const* d_in, const int* in_sizes, int n_in,
                              void* d_out, int out_size, void* d_ws, size_t ws_size,
                              hipStream_t stream) {
  const float* x = (const float*)d_in[0];   // [M, K]
  const float* A = (const float*)d_in[1];   // [K, RANK]
  const float* B = (const float*)d_in[2];   // [RANK, N]
  float* out = (float*)d_out;               // [M, N]
  float* Tp = (float*)d_ws;                 // [NPART, M, RANK] scratch (4 MiB)

  // Kernel 1: grid (M/32 row-groups, 4 K-quarters), 512-thread blocks.
  lora_xa<<<dim3(M / ROWSB, NPART), 512, 0, stream>>>(x, A, Tp);

  // Kernel 2: grid (N/1024, M/ROWS2).
  lora_tb<<<dim3(N / 1024, M / ROWS2), 256, 0, stream>>>(Tp, B, out);
}

// Round 7
// 148.702 us; speedup vs baseline: 1.9788x; 1.0929x over previous
//
#include <hip/hip_runtime.h>

// LoRA: out = x @ (A@B) * 1.0, computed as (x@A)@B.
// x: [M=16384, K=4096] f32, A: [K, 16] f32, B: [16, N=4096] f32.
constexpr int RANK = 16;
constexpr int K = 4096;
constexpr int N = 4096;
constexpr int M = 4 * 4096;
constexpr int KC = 256;          // K-chunk staged in LDS (16 x 256 floats = 16KB)
constexpr int NCHUNK = K / KC;   // 16
constexpr int ROWSB = 8;         // rows per block (4 waves x 2 rows)
constexpr int ROWS2 = 32;        // rows per block in kernel 2

// ---------------- Kernel 1: T = x @ A ----------------
// Occupancy-first design: 2 rows/wave -> vals[32]; target <=64 VGPR so
// 8 blocks/CU (32 waves) co-reside (16KB LDS x 8 = 128KB). Per chunk each
// lane owns ONE k-quad:
//   - x loads: float4, 64 lanes x 16B = 1KB contiguous per row, coalesced
//   - A reads: AsT4[j*64 + (lane ^ (j>>2))] -- store-side swizzle
//     kpos = k ^ ((j>>2)<<2) is an involution on k-bits 2..3, so lanes read
//     a permutation of 64 consecutive 16B slots -> conflict-free ds_read_b128.
//   - staging writes: <=2-way bank conflict (free), tiny volume.
// Epilogue: 5-fold reduce-scatter over lane bits {32,16,8,4,2} (31 shuffles)
// -> lane pair (2m, 2m+1) holds COMPLEMENTARY partials of element m; final
// butterfly over lane bit 1 completes the sum (r6 bug: this was missing).

__global__ __launch_bounds__(256) void lora_xa(const float* __restrict__ x,
                                               const float* __restrict__ A,
                                               float* __restrict__ T) {
  const int tid = threadIdx.x;
  const int lane = tid & 63;
  const int wave = tid >> 6;
  const int r0 = blockIdx.x * ROWSB + wave * 2;  // this wave's 2 rows

  __shared__ float AsT[RANK][KC];  // 16 KB, transposed + swizzled A chunk
  float4* __restrict__ AsT4 = reinterpret_cast<float4*>(&AsT[0][0]);  // [16][64]

  const float4* __restrict__ A4 = reinterpret_cast<const float4*>(A);
  const float4* __restrict__ x4 = reinterpret_cast<const float4*>(x);

  float vals[32];
#pragma unroll
  for (int i = 0; i < 32; ++i) vals[i] = 0.0f;

  for (int c = 0; c < NCHUNK; ++c) {
    __syncthreads();  // previous chunk's readers done
    // ---- stage chunk c: KC*16 floats = 1024 float4, 4 per thread ----
#pragma unroll
    for (int q = 0; q < 4; ++q) {
      const int n = q * 256 + tid;   // n = k*4 + s, 0..1023
      const int k = n >> 2;          // local k row 0..255
      const int s = n & 3;           // j-group (cols 4s..4s+3)
      const float4 v = A4[c * 1024 + n];  // coalesced
      const int kp = k ^ (s << 2);   // swizzle (s == j>>2 for these 4 j's)
      AsT[4 * s + 0][kp] = v.x;
      AsT[4 * s + 1][kp] = v.y;
      AsT[4 * s + 2][kp] = v.z;
      AsT[4 * s + 3][kp] = v.w;
    }
    __syncthreads();

    // ---- compute: one k-quad per lane, 2 rows ----
    const float4 xv0 = x4[(size_t)(r0 + 0) * (K / 4) + c * (KC / 4) + lane];
    const float4 xv1 = x4[(size_t)(r0 + 1) * (K / 4) + c * (KC / 4) + lane];

#pragma unroll
    for (int j = 0; j < RANK; ++j) {
      const float4 a = AsT4[j * (KC / 4) + (lane ^ (j >> 2))];  // swizzle-inv
      float acc0 = vals[j];
      float acc1 = vals[16 + j];
      acc0 = fmaf(xv0.x, a.x, acc0);
      acc0 = fmaf(xv0.y, a.y, acc0);
      acc0 = fmaf(xv0.z, a.z, acc0);
      acc0 = fmaf(xv0.w, a.w, acc0);
      acc1 = fmaf(xv1.x, a.x, acc1);
      acc1 = fmaf(xv1.y, a.y, acc1);
      acc1 = fmaf(xv1.z, a.z, acc1);
      acc1 = fmaf(xv1.w, a.w, acc1);
      vals[j] = acc0;
      vals[16 + j] = acc1;
    }
  }

  // 5-fold recursive-halving reduce-scatter (31 shuffles) over lane bits
  // {32,16,8,4,2}. After the folds, lane l holds element e=(l>>1) summed over
  // all lanes agreeing in bit 0 -- lanes 2m and 2m+1 hold complementary
  // partials of element m. Final butterfly over bit 1 completes the sum.
#define FOLD(AH, LB)                                           \
  {                                                            \
    const bool hi = (lane & (LB)) != 0;                        \
    _Pragma("unroll")                                          \
    for (int i = 0; i < (AH); ++i) {                           \
      const float send = hi ? vals[i] : vals[i + (AH)];        \
      const float keep = hi ? vals[i + (AH)] : vals[i];        \
      vals[i] = keep + __shfl_xor(send, (LB), 64);             \
    }                                                          \
  }
  FOLD(16, 32)
  FOLD(8, 16)
  FOLD(4, 8)
  FOLD(2, 4)
  FOLD(1, 2)
#undef FOLD
  vals[0] += __shfl_xor(vals[0], 1, 64);  // fold the remaining lane bit 0

  if (!(lane & 1)) {
    const int e = lane >> 1;  // 0..31
    T[(size_t)(r0 + (e >> 4)) * RANK + (e & 15)] = vals[0];
  }
}

// ---------------- Kernel 2: out = T @ B ----------------
// Exact r2 version (measured at/near the ~6.9 TB/s write ceiling).
__global__ __launch_bounds__(256) void lora_tb(const float* __restrict__ T,
                                               const float* __restrict__ B,
                                               float* __restrict__ out) {
  const int n0 = blockIdx.x * 1024 + threadIdx.x * 4;
  const int r0 = blockIdx.y * ROWS2;

  const float4* __restrict__ B4 = reinterpret_cast<const float4*>(B);
  float4* __restrict__ out4 = reinterpret_cast<float4*>(out);

  float4 b[16];
#pragma unroll
  for (int j = 0; j < RANK; ++j) b[j] = B4[((size_t)j * N + n0) >> 2];

  for (int r = 0; r < ROWS2; ++r) {
    const float* __restrict__ t = T + (size_t)(r0 + r) * RANK;
    float4 acc;
    acc.x = acc.y = acc.z = acc.w = 0.0f;
#pragma unroll
    for (int j = 0; j < RANK; ++j) {
      const float ts = t[j];
      acc.x = fmaf(ts, b[j].x, acc.x);
      acc.y = fmaf(ts, b[j].y, acc.y);
      acc.z = fmaf(ts, b[j].z, acc.z);
      acc.w = fmaf(ts, b[j].w, acc.w);
    }
    out4[((size_t)(r0 + r) * N + n0) >> 2] = acc;
  }
}

extern "C" void kernel_launch(void* const* d_in, const int* in_sizes, int n_in,
                              void* d_out, int out_size, void* d_ws, size_t ws_size,
                              hipStream_t stream) {
  const float* x = (const float*)d_in[0];   // [M, K]
  const float* A = (const float*)d_in[1];   // [K, RANK]
  const float* B = (const float*)d_in[2];   // [RANK, N]
  float* out = (float*)d_out;               // [M, N]
  float* T = (float*)d_ws;                  // [M, RANK] scratch (1 MiB)

  // Kernel 1: 8 rows per block (4 waves x 2 rows) -> 2048 blocks.
  lora_xa<<<M / ROWSB, 256, 0, stream>>>(x, A, T);

  // Kernel 2: grid (N/1024, M/ROWS2).
  lora_tb<<<dim3(N / 1024, M / ROWS2), 256, 0, stream>>>(T, B, out);
}

// Round 8
// 141.584 us; speedup vs baseline: 2.0783x; 1.0503x over previous
//
#include <hip/hip_runtime.h>

// LoRA: out = x @ (A@B) * 1.0, computed as (x@A)@B.
// x: [M=16384, K=4096] f32, A: [K, 16] f32, B: [16, N=4096] f32.
constexpr int RANK = 16;
constexpr int K = 4096;
constexpr int N = 4096;
constexpr int M = 4 * 4096;
constexpr int KC = 512;       // K-chunk staged in LDS (512 rows x 64B = 32KB)
constexpr int NCHUNK = K / KC;
constexpr int ROWS2 = 32;     // rows per block in kernel 2

// ---------------- Kernel 1: T = x @ A ----------------
// r2 skeleton (best: 133us total) with ONE change: x loads are float4
// (lane owns k-quad 4l..4l+3) to quadruple in-flight read bytes per issue
// slot. A-tile LDS layout, swizzle, staging, barriers, FMA count, and the
// reduce-scatter epilogue are bit-for-bit r2.
//
// LDS swizzle (unchanged): slot s of row k stored at p = s ^ ((k>>2)&3).
// New read pattern: lane l reads rows 4*lq+i (lq = kb2*64+l) at slot
// s ^ (l&3); since (row>>2)&3 == l&3, retrieved slot is exactly s
// (lane-uniform j). Bank check per b128 phase (8 consecutive lanes):
// bank = (16*i + 4*(s^(l&3))) mod 32 -> 4 distinct slots x 2 lanes
// = 2-way = free (m136).

__global__ __launch_bounds__(256) void lora_xa(const float* __restrict__ x,
                                               const float* __restrict__ A,
                                               float* __restrict__ T) {
  const int lane = threadIdx.x & 63;
  const int tid = threadIdx.x;
  const int wave = tid >> 6;
  const int r0 = blockIdx.x * 16 + wave * 4;  // this wave's 4 rows
  const int m = lane & 3;

  __shared__ float4 As[KC * 4];  // 32 KB, swizzled slots (r2 layout)

  const float4* __restrict__ A4 = reinterpret_cast<const float4*>(A);
  const float4* __restrict__ x4 = reinterpret_cast<const float4*>(x);

  float vals[64];
#pragma unroll
  for (int i = 0; i < 64; ++i) vals[i] = 0.0f;

  for (int c = 0; c < NCHUNK; ++c) {
    __syncthreads();  // previous chunk's readers done
    // ---- stage chunk c: KC*4 = 2048 float4 slots, 8 per thread (r2) ----
#pragma unroll
    for (int q = 0; q < 8; ++q) {
      const int n = q * 256 + tid;              // slot index 0..2047
      const int k = n >> 2;                     // local row
      const int s = n & 3;                      // true slot
      const int p = s ^ ((k >> 2) & 3);         // swizzled position
      As[k * 4 + p] = A4[(size_t)c * 2048 + n];
    }
    __syncthreads();

    // ---- compute: 2 sub-blocks of 64 k-quads (one quad per lane) ----
#pragma unroll
    for (int kb2 = 0; kb2 < 2; ++kb2) {
      const int lq = kb2 * 64 + lane;  // local k-quad; rows 4lq..4lq+3

      // float4 x loads: 16B/lane, coalesced, 4KB in flight per wave here
      float4 xv[4];
#pragma unroll
      for (int r = 0; r < 4; ++r)
        xv[r] = x4[(size_t)(r0 + r) * (K / 4) + c * (KC / 4) + lq];

#pragma unroll
      for (int i = 0; i < 4; ++i) {
        const int row = 4 * lq + i;
        float4 a[4];
#pragma unroll
        for (int s = 0; s < 4; ++s) a[s] = As[row * 4 + (s ^ m)];

#pragma unroll
        for (int r = 0; r < 4; ++r) {
          const float xs = (i == 0) ? xv[r].x : (i == 1) ? xv[r].y
                          : (i == 2) ? xv[r].z : xv[r].w;
#pragma unroll
          for (int s = 0; s < 4; ++s) {
            vals[r * 16 + 4 * s + 0] = fmaf(xs, a[s].x, vals[r * 16 + 4 * s + 0]);
            vals[r * 16 + 4 * s + 1] = fmaf(xs, a[s].y, vals[r * 16 + 4 * s + 1]);
            vals[r * 16 + 4 * s + 2] = fmaf(xs, a[s].z, vals[r * 16 + 4 * s + 2]);
            vals[r * 16 + 4 * s + 3] = fmaf(xs, a[s].w, vals[r * 16 + 4 * s + 3]);
          }
        }
      }
    }
  }

  // Recursive-halving reduce-scatter across the 64 lanes (r2, proven).
  // After all steps, lane i holds the fully-summed element i (r=i>>4, j=i&15).
#define RSTEP(HALF)                                            \
  {                                                            \
    const bool hi = (lane & (HALF)) != 0;                      \
    _Pragma("unroll")                                          \
    for (int i = 0; i < (HALF); ++i) {                         \
      const float send = hi ? vals[i] : vals[i + (HALF)];      \
      const float keep = hi ? vals[i + (HALF)] : vals[i];      \
      vals[i] = keep + __shfl_xor(send, (HALF), 64);           \
    }                                                          \
  }
  RSTEP(32)
  RSTEP(16)
  RSTEP(8)
  RSTEP(4)
  RSTEP(2)
  RSTEP(1)
#undef RSTEP

  T[(size_t)(r0 + (lane >> 4)) * RANK + (lane & 15)] = vals[0];
}

// ---------------- Kernel 2: out = T @ B ----------------
// Exact r2 version (measured at/near the ~6.9 TB/s write ceiling).
__global__ __launch_bounds__(256) void lora_tb(const float* __restrict__ T,
                                               const float* __restrict__ B,
                                               float* __restrict__ out) {
  const int n0 = blockIdx.x * 1024 + threadIdx.x * 4;
  const int r0 = blockIdx.y * ROWS2;

  const float4* __restrict__ B4 = reinterpret_cast<const float4*>(B);
  float4* __restrict__ out4 = reinterpret_cast<float4*>(out);

  float4 b[16];
#pragma unroll
  for (int j = 0; j < RANK; ++j) b[j] = B4[((size_t)j * N + n0) >> 2];

  for (int r = 0; r < ROWS2; ++r) {
    const float* __restrict__ t = T + (size_t)(r0 + r) * RANK;
    float4 acc;
    acc.x = acc.y = acc.z = acc.w = 0.0f;
#pragma unroll
    for (int j = 0; j < RANK; ++j) {
      const float ts = t[j];
      acc.x = fmaf(ts, b[j].x, acc.x);
      acc.y = fmaf(ts, b[j].y, acc.y);
      acc.z = fmaf(ts, b[j].z, acc.z);
      acc.w = fmaf(ts, b[j].w, acc.w);
    }
    out4[((size_t)(r0 + r) * N + n0) >> 2] = acc;
  }
}

extern "C" void kernel_launch(void* const* d_in, const int* in_sizes, int n_in,
                              void* d_out, int out_size, void* d_ws, size_t ws_size,
                              hipStream_t stream) {
  const float* x = (const float*)d_in[0];   // [M, K]
  const float* A = (const float*)d_in[1];   // [K, RANK]
  const float* B = (const float*)d_in[2];   // [RANK, N]
  float* out = (float*)d_out;               // [M, N]
  float* T = (float*)d_ws;                  // [M, RANK] scratch (1 MiB)

  // Kernel 1: 16 rows per block (4 waves x 4 rows) -> 1024 blocks.
  lora_xa<<<M / 16, 256, 0, stream>>>(x, A, T);

  // Kernel 2: grid (N/1024, M/ROWS2).
  lora_tb<<<dim3(N / 1024, M / ROWS2), 256, 0, stream>>>(T, B, out);
}

// Round 9
// 129.655 us; speedup vs baseline: 2.2695x; 1.0920x over previous
//
#include <hip/hip_runtime.h>

// LoRA: out = x @ (A@B) * 1.0, computed as (x@A)@B, FUSED in one kernel.
// x: [M=16384, K=4096] f32, A: [K, 16] f32, B: [16, N=4096] f32.
// Phase 1 (per block of 16 rows): T-tile = x-rows @ A  (r2's proven xa).
// Phase 2: out-rows = T-tile @ B, wave w owns col-chunk w*1024.
// Fusion overlaps the HBM read stream (phase 1) of some resident blocks with
// the HBM write stream (phase 2) of others; no T round-trip, one launch.
constexpr int RANK = 16;
constexpr int K = 4096;
constexpr int N = 4096;
constexpr int M = 4 * 4096;
constexpr int KC = 512;       // K-chunk staged in LDS (512 rows x 64B = 32KB)
constexpr int NCHUNK = K / KC;

__global__ __launch_bounds__(256) void lora_fused(const float* __restrict__ x,
                                                  const float* __restrict__ A,
                                                  const float* __restrict__ B,
                                                  float* __restrict__ out) {
  const int lane = threadIdx.x & 63;
  const int tid = threadIdx.x;
  const int wave = tid >> 6;
  const int rbase = blockIdx.x * 16;
  const int r0 = rbase + wave * 4;  // this wave's 4 rows (phase 1)

  __shared__ float4 As[KC * 4];     // 32 KB, swizzled A chunk (r2 layout)
  __shared__ float Ts[16][RANK];    // 1 KB, block's T-tile

  const float4* __restrict__ A4 = reinterpret_cast<const float4*>(A);

  // ================= Phase 1: T-tile = x @ A (bit-for-bit r2) =============
  float vals[64];
#pragma unroll
  for (int i = 0; i < 64; ++i) vals[i] = 0.0f;

  for (int c = 0; c < NCHUNK; ++c) {
    __syncthreads();  // previous chunk's readers done
    // ---- stage chunk c: KC*4 = 2048 float4 slots, 8 per thread ----
    // slot s of row k stored at p = s ^ ((k>>2)&3)
#pragma unroll
    for (int q = 0; q < 8; ++q) {
      const int n = q * 256 + tid;              // slot index 0..2047
      const int k = n >> 2;                     // local row
      const int s = n & 3;                      // true slot
      const int p = s ^ ((k >> 2) & 3);         // swizzled position
      As[k * 4 + p] = A4[(size_t)c * 2048 + n];
    }
    __syncthreads();

    // ---- compute: 8 k-blocks of 64 (one k per lane) ----
    const int m = (lane >> 2) & 3;
#pragma unroll
    for (int kbi = 0; kbi < 8; ++kbi) {
      const int kl = kbi * 64 + lane;           // local k in chunk
      const size_t kg = (size_t)c * KC + kl;    // global k

      float xv[4];
#pragma unroll
      for (int r = 0; r < 4; ++r) xv[r] = x[(size_t)(r0 + r) * K + kg];

      float4 a[4];
#pragma unroll
      for (int s = 0; s < 4; ++s) a[s] = As[kl * 4 + (s ^ m)];

#pragma unroll
      for (int r = 0; r < 4; ++r) {
#pragma unroll
        for (int s = 0; s < 4; ++s) {
          vals[r * 16 + 4 * s + 0] = fmaf(xv[r], a[s].x, vals[r * 16 + 4 * s + 0]);
          vals[r * 16 + 4 * s + 1] = fmaf(xv[r], a[s].y, vals[r * 16 + 4 * s + 1]);
          vals[r * 16 + 4 * s + 2] = fmaf(xv[r], a[s].z, vals[r * 16 + 4 * s + 2]);
          vals[r * 16 + 4 * s + 3] = fmaf(xv[r], a[s].w, vals[r * 16 + 4 * s + 3]);
        }
      }
    }
  }

  // Reduce-scatter (r2, proven): lane i ends with element i (r=i>>4, j=i&15).
#define RSTEP(HALF)                                            \
  {                                                            \
    const bool hi = (lane & (HALF)) != 0;                      \
    _Pragma("unroll")                                          \
    for (int i = 0; i < (HALF); ++i) {                         \
      const float send = hi ? vals[i] : vals[i + (HALF)];      \
      const float keep = hi ? vals[i + (HALF)] : vals[i];      \
      vals[i] = keep + __shfl_xor(send, (HALF), 64);           \
    }                                                          \
  }
  RSTEP(32)
  RSTEP(16)
  RSTEP(8)
  RSTEP(4)
  RSTEP(2)
  RSTEP(1)
#undef RSTEP

  // Hand off T-tile via LDS (1 write/lane, conflict-free).
  Ts[wave * 4 + (lane >> 4)][lane & 15] = vals[0];
  __syncthreads();

  // ================= Phase 2: out-tile = T-tile @ B (tb structure) ========
  // Wave w owns columns [w*1024, w*1024+1024); B fragment loaded ONCE.
  const int n0 = wave * 1024 + lane * 4;  // wait: lane*4 covers 256 cols/wave
  // Each wave has 64 lanes * 4 cols = 256 cols per pass -> 4 passes of 256.
  const float4* __restrict__ B4 = reinterpret_cast<const float4*>(B);
  float4* __restrict__ out4 = reinterpret_cast<float4*>(out);

#pragma unroll 1
  for (int cc = 0; cc < 4; ++cc) {
    const int col = wave * 1024 + cc * 256 + lane * 4;

    float4 b[16];
#pragma unroll
    for (int j = 0; j < RANK; ++j) b[j] = B4[((size_t)j * N + col) >> 2];

#pragma unroll 1
    for (int r = 0; r < 16; ++r) {
      // Broadcast T row r (same addr all lanes -> free LDS broadcast).
      const float4* __restrict__ tr4 =
          reinterpret_cast<const float4*>(&Ts[r][0]);
      const float4 t0 = tr4[0];
      const float4 t1 = tr4[1];
      const float4 t2 = tr4[2];
      const float4 t3 = tr4[3];

      float4 acc;
      acc.x = acc.y = acc.z = acc.w = 0.0f;
      const float tsv[16] = {t0.x, t0.y, t0.z, t0.w, t1.x, t1.y, t1.z, t1.w,
                             t2.x, t2.y, t2.z, t2.w, t3.x, t3.y, t3.z, t3.w};
#pragma unroll
      for (int j = 0; j < RANK; ++j) {
        acc.x = fmaf(tsv[j], b[j].x, acc.x);
        acc.y = fmaf(tsv[j], b[j].y, acc.y);
        acc.z = fmaf(tsv[j], b[j].z, acc.z);
        acc.w = fmaf(tsv[j], b[j].w, acc.w);
      }
      out4[((size_t)(rbase + r) * N + col) >> 2] = acc;
    }
  }
  (void)n0;
}

extern "C" void kernel_launch(void* const* d_in, const int* in_sizes, int n_in,
                              void* d_out, int out_size, void* d_ws, size_t ws_size,
                              hipStream_t stream) {
  const float* x = (const float*)d_in[0];   // [M, K]
  const float* A = (const float*)d_in[1];   // [K, RANK]
  const float* B = (const float*)d_in[2];   // [RANK, N]
  float* out = (float*)d_out;               // [M, N]
  (void)d_ws; (void)ws_size;

  // One fused kernel: 16 rows per block -> 1024 blocks.
  lora_fused<<<M / 16, 256, 0, stream>>>(x, A, B, out);
}